// Round 12
// baseline (323.775 us; speedup 1.0000x reference)
//
#include <hip/hip_runtime.h>
#include <hip/hip_bf16.h>
#include <stdint.h>

#define B_ 256
#define T_ 512
#define C_ 14
#define CO_ 32
#define H_ 128
#define G_ 512   // 4*H

__device__ __forceinline__ float sigm_fast(float x) {
  float e = __expf(-x);
  return __builtin_amdgcn_rcpf(1.f + e);
}
__device__ __forceinline__ float tanh_fast(float x) {
  float e = __expf(2.f * x);               // inf-safe: x>>0 -> 1, x<<0 -> -1
  return 1.f - 2.f * __builtin_amdgcn_rcpf(1.f + e);
}

// Fast path is provable: mem = o*tanh(syn) - reset*thr < 1 always (o<1,
// |tanh|<1). Spike needs mem - thr1 > 0, impossible when thr1 >= 1, so
// layer-1 spikes are identically zero for ANY x/weights.

// ---------------- Kernel 1: conv over time + Leaky spike (fallback) --------
__global__ __launch_bounds__(256) void k_conv_spike(
    const float* __restrict__ thr1_p, const float* __restrict__ x,
    const float* __restrict__ cw, const float* __restrict__ cb,
    unsigned int* __restrict__ cur1) {
  if (thr1_p[0] >= 1.0f) return;
  __shared__ float w_s[CO_ * C_ * 3];
  __shared__ float b_s[CO_];
  for (int i = threadIdx.x; i < CO_ * C_ * 3; i += blockDim.x) w_s[i] = cw[i];
  if (threadIdx.x < CO_) b_s[threadIdx.x] = cb[threadIdx.x];
  __syncthreads();
  int idx = blockIdx.x * blockDim.x + threadIdx.x;  // b*T + t
  if (idx >= B_ * T_) return;
  int b = idx / T_, t = idx % T_;
  float xin[3][C_];
#pragma unroll
  for (int k = 0; k < 3; ++k) {
    int tt = t + k - 1;
    if (tt < 0 || tt >= T_) {
#pragma unroll
      for (int c = 0; c < C_; ++c) xin[k][c] = 0.f;
    } else {
      const float* p = x + ((size_t)b * T_ + tt) * C_;
#pragma unroll
      for (int c = 0; c < C_; ++c) xin[k][c] = p[c];
    }
  }
  unsigned int bits = 0u;
  for (int oc = 0; oc < CO_; ++oc) {
    float s = b_s[oc];
    const float* wr = &w_s[oc * C_ * 3];
#pragma unroll
    for (int ic = 0; ic < C_; ++ic)
#pragma unroll
      for (int k = 0; k < 3; ++k) s = fmaf(xin[k][ic], wr[ic * 3 + k], s);
    if (s - 1.0f > 0.f) bits |= (1u << oc);
  }
  cur1[idx] = bits;
}

// ---------------- Kernel 2: honest SLSTM layer 1 (fallback only) -----------
__global__ __launch_bounds__(512, 2) void k_slstm1(
    const unsigned int* __restrict__ cur1,
    const float* __restrict__ w_ih, const float* __restrict__ w_hh,
    const float* __restrict__ b_ih, const float* __restrict__ b_hh,
    const float* __restrict__ thr_p, unsigned long long* __restrict__ spk_bits,
    unsigned int* __restrict__ count) {
  if (thr_p[0] >= 1.0f) return;  // spikes provably zero; count stays 0
  const int g = threadIdx.x;
  const int t0 = blockIdx.x * 2;
  const float thr = thr_p[0];
  float wih[32], whh[H_];
#pragma unroll
  for (int k = 0; k < 32; ++k) wih[k] = w_ih[g * 32 + k];
#pragma unroll
  for (int k = 0; k < H_; ++k) whh[k] = w_hh[g * H_ + k];
  const float bias = b_ih[g] + b_hh[g];
  __shared__ float mem_s[2][H_];
  __shared__ float gate_s[2][G_];
  float syn = 0.f;
  int cnt = 0;
  if (g < 256) mem_s[g >> 7][g & 127] = 0.f;
  __syncthreads();
  for (int b = 0; b < B_; ++b) {
    unsigned int bits0 = cur1[b * T_ + t0];
    unsigned int bits1 = cur1[b * T_ + t0 + 1];
    float s0 = bias, s1 = bias;
#pragma unroll
    for (int k = 0; k < 32; ++k) {
      s0 += ((bits0 >> k) & 1u) ? wih[k] : 0.f;
      s1 += ((bits1 >> k) & 1u) ? wih[k] : 0.f;
    }
#pragma unroll
    for (int k = 0; k < H_; ++k) {
      s0 = fmaf(whh[k], mem_s[0][k], s0);
      s1 = fmaf(whh[k], mem_s[1][k], s1);
    }
    gate_s[0][g] = s0;
    gate_s[1][g] = s1;
    __syncthreads();
    if (g < 256) {
      const int r = g >> 7, h = g & 127;
      float gi = gate_s[r][h];
      float gf = gate_s[r][h + 128];
      float gg = gate_s[r][h + 256];
      float go = gate_s[r][h + 384];
      float ii = 1.f / (1.f + expf(-gi));
      float ff = 1.f / (1.f + expf(-gf));
      float gt = tanhf(gg);
      float oo = 1.f / (1.f + expf(-go));
      float memp = mem_s[r][h];
      float rst = (memp - thr > 0.f) ? thr : 0.f;
      syn = ff * syn + ii * gt;
      float mm = oo * tanhf(syn) - rst;
      mem_s[r][h] = mm;
      bool spk = (mm - thr) > 0.f;
      cnt += spk ? 1 : 0;
      unsigned long long m = __ballot(spk);
      if ((g & 63) == 0)
        spk_bits[((size_t)b * T_ + t0 + r) * 2 + ((h >> 6) & 1)] = m;
    }
    __syncthreads();
  }
  if (g < 256) atomicAdd(&count[g & 127], (unsigned int)cnt);
}

// ---------------- Kernel 3: BN params from spike counts (both paths) -------
__global__ void k_bnprep(const unsigned int* __restrict__ count,
                         const float* __restrict__ gamma,
                         const float* __restrict__ beta,
                         float* __restrict__ a, float* __restrict__ c) {
  int h = threadIdx.x;
  if (h >= H_) return;
  const float inv_n = 1.f / (float)(B_ * T_);
  float mu = (float)count[h] * inv_n;
  float var = mu * (1.f - mu);
  float ai = gamma[h] / sqrtf(var + 1e-5f);
  a[h] = ai;
  c[h] = beta[h] - mu * ai;
}

// ---------------- Kernel 4: fold BN into layer-2 weights (cg both paths) ---
__global__ void k_fold(const float* __restrict__ thr1_p,
                       const float* __restrict__ w_ih2,
                       const float* __restrict__ b_ih2,
                       const float* __restrict__ b_hh2,
                       const float* __restrict__ a, const float* __restrict__ c,
                       float* __restrict__ W2p, float* __restrict__ cg) {
  int gi = blockIdx.x * blockDim.x + threadIdx.x;  // 0..511
  if (gi >= G_) return;
  const int fast = thr1_p[0] >= 1.0f;
  float s = b_ih2[gi] + b_hh2[gi];
  for (int h = 0; h < H_; ++h) {
    float w = w_ih2[gi * H_ + h];
    if (!fast) W2p[h * G_ + gi] = w * a[h];  // fallback-only matrix
    s = fmaf(w, c[h], s);
  }
  cg[gi] = s;
}

// ---------------- Kernel 5: honest SLSTM layer 2 (fallback only) -----------
__global__ __launch_bounds__(512, 2) void k_slstm2(
    const float* __restrict__ thr1_p,
    const unsigned long long* __restrict__ spk_bits,
    const float* __restrict__ w_hh, const float* __restrict__ W2p,
    const float* __restrict__ cg, const float* __restrict__ thr_p,
    float* __restrict__ acc_out) {
  if (thr1_p[0] >= 1.0f) return;  // fast path handled by k_traj
  const int g = threadIdx.x;
  const int t0 = blockIdx.x * 2;
  const float thr = thr_p[0];
  float whh[H_];
#pragma unroll
  for (int k = 0; k < H_; ++k) whh[k] = w_hh[g * H_ + k];
  const float bias = cg[g];
  __shared__ float mem_s[2][H_];
  __shared__ float gate_s[2][G_];
  float syn = 0.f, accv = 0.f;
  if (g < 256) mem_s[g >> 7][g & 127] = 0.f;
  __syncthreads();
  for (int b = 0; b < B_; ++b) {
    unsigned long long m00 = spk_bits[((size_t)b * T_ + t0) * 2 + 0];
    unsigned long long m01 = spk_bits[((size_t)b * T_ + t0) * 2 + 1];
    unsigned long long m10 = spk_bits[((size_t)b * T_ + t0 + 1) * 2 + 0];
    unsigned long long m11 = spk_bits[((size_t)b * T_ + t0 + 1) * 2 + 1];
    float s0 = bias, s1 = bias;
    while (m00) { int h = __ffsll(m00) - 1; m00 &= m00 - 1; s0 += W2p[h * G_ + g]; }
    while (m01) { int h = __ffsll(m01) - 1; m01 &= m01 - 1; s0 += W2p[(h + 64) * G_ + g]; }
    while (m10) { int h = __ffsll(m10) - 1; m10 &= m10 - 1; s1 += W2p[h * G_ + g]; }
    while (m11) { int h = __ffsll(m11) - 1; m11 &= m11 - 1; s1 += W2p[(h + 64) * G_ + g]; }
#pragma unroll
    for (int k = 0; k < H_; ++k) {
      s0 = fmaf(whh[k], mem_s[0][k], s0);
      s1 = fmaf(whh[k], mem_s[1][k], s1);
    }
    gate_s[0][g] = s0;
    gate_s[1][g] = s1;
    __syncthreads();
    if (g < 256) {
      const int r = g >> 7, h = g & 127;
      float gi = gate_s[r][h];
      float gf = gate_s[r][h + 128];
      float gg = gate_s[r][h + 256];
      float go = gate_s[r][h + 384];
      float ii = 1.f / (1.f + expf(-gi));
      float ff = 1.f / (1.f + expf(-gf));
      float gt = tanhf(gg);
      float oo = 1.f / (1.f + expf(-go));
      float memp = mem_s[r][h];
      float rst = (memp - thr > 0.f) ? thr : 0.f;
      syn = ff * syn + ii * gt;
      float mm = oo * tanhf(syn) - rst;
      mem_s[r][h] = mm;
      accv += mm;
    }
    __syncthreads();
  }
  if (g < 256) acc_out[(size_t)(t0 + (g >> 7)) * H_ + (g & 127)] = accv;
}

// ---------------- Kernel 5b: FAST layer 2 — single shared trajectory -------
// thr1>=1 -> layer-2 input = beta every row/step -> ONE 256-step trajectory.
// 1024 threads, HALF a gate per thread: g = i&511, hf = i>>9 (wave-uniform).
// 64 weights/thread in 16 named float4 + ONE-TIME pins -> live set ~105
// fits the 128 ARCH VGPRs of waves_per_eu(4,4): no AGPR parking, no copy
// bounces (r11 lesson: 128 wt/thread @ 256-budget -> AGPRs + per-FMA cost).
// Each thread needs only ONE vm (its 64-wide half of mem): 64 readlanes.
// Halves combine through double-buffered part_s; phase 2 replicated per
// wave (each lane owns h = hf*64 + lane), mem never touches LDS; ONE
// barrier per step.
#define PIN4(v) asm volatile("" : "+v"(v.x), "+v"(v.y), "+v"(v.z), "+v"(v.w))
#define PIN16(P) PIN4(P##0); PIN4(P##1); PIN4(P##2); PIN4(P##3);

#define LD16(P, p, o)                              \
  float4 P##0 = *(const float4*)((p) + (o));       \
  float4 P##1 = *(const float4*)((p) + (o) + 4);   \
  float4 P##2 = *(const float4*)((p) + (o) + 8);   \
  float4 P##3 = *(const float4*)((p) + (o) + 12);

#define RLF(v, k) __uint_as_float(__builtin_amdgcn_readlane((v), (k)))

// NOTE: (P##0).x — parens required; "P##0.x" lexes "0.x" as one pp-number.
#define DOT16(P, vmx, base) {                          \
    float mk;                                          \
    mk = RLF(vmx, (base) + 0);  a0 = fmaf((P##0).x, mk, a0); \
    mk = RLF(vmx, (base) + 1);  a1 = fmaf((P##0).y, mk, a1); \
    mk = RLF(vmx, (base) + 2);  a2 = fmaf((P##0).z, mk, a2); \
    mk = RLF(vmx, (base) + 3);  a3 = fmaf((P##0).w, mk, a3); \
    mk = RLF(vmx, (base) + 4);  a0 = fmaf((P##1).x, mk, a0); \
    mk = RLF(vmx, (base) + 5);  a1 = fmaf((P##1).y, mk, a1); \
    mk = RLF(vmx, (base) + 6);  a2 = fmaf((P##1).z, mk, a2); \
    mk = RLF(vmx, (base) + 7);  a3 = fmaf((P##1).w, mk, a3); \
    mk = RLF(vmx, (base) + 8);  a0 = fmaf((P##2).x, mk, a0); \
    mk = RLF(vmx, (base) + 9);  a1 = fmaf((P##2).y, mk, a1); \
    mk = RLF(vmx, (base) + 10); a2 = fmaf((P##2).z, mk, a2); \
    mk = RLF(vmx, (base) + 11); a3 = fmaf((P##2).w, mk, a3); \
    mk = RLF(vmx, (base) + 12); a0 = fmaf((P##3).x, mk, a0); \
    mk = RLF(vmx, (base) + 13); a1 = fmaf((P##3).y, mk, a1); \
    mk = RLF(vmx, (base) + 14); a2 = fmaf((P##3).z, mk, a2); \
    mk = RLF(vmx, (base) + 15); a3 = fmaf((P##3).w, mk, a3); \
  }

__global__ __launch_bounds__(1024)
__attribute__((amdgpu_waves_per_eu(4, 4))) void k_traj(
    const float* __restrict__ thr1_p, const float* __restrict__ w_hh,
    const float* __restrict__ cg, const float* __restrict__ thr_p,
    const float* __restrict__ fc_w, const float* __restrict__ fc_b,
    float* __restrict__ out) {
  if (thr1_p[0] < 1.0f) return;
  const int i = threadIdx.x;
  const int g = i & 511;     // gate
  const int hf = i >> 9;     // half (wave-uniform: waves 0-7 -> 0, 8-15 -> 1)
  const int lane = i & 63;
  const int h_own = (hf << 6) + lane;   // this thread's hidden index
  const float thr = thr_p[0];

  const float* wr = w_hh + (size_t)g * H_ + (hf << 6);
  LD16(Pa, wr, 0) LD16(Pb, wr, 16) LD16(Pc, wr, 32) LD16(Pd, wr, 48)
  float bias = hf ? 0.f : cg[g];
  // ONE-TIME pins: weights become asm-defined (non-rematerializable),
  // stay register-resident across the loop at zero per-iteration cost.
  PIN16(Pa) PIN16(Pb) PIN16(Pc) PIN16(Pd)
  asm volatile("" : "+v"(bias));

  __shared__ float part_s[2][2][G_];  // [buf][hf][gate] partial preacts
  __shared__ float red_s[H_ + 8];
  float syn = 0.f, memp = 0.f, accm = 0.f;
  int vm = 0;  // bits of mem[hf*64 + lane]; mem_0 = 0

  for (int b = 0; b < B_; ++b) {
    // phase 1: 64-wide half-dot for gate g; operands via readlane (SGPR)
    float a0 = bias, a1 = 0.f, a2 = 0.f, a3 = 0.f;
    DOT16(Pa, vm, 0) DOT16(Pb, vm, 16) DOT16(Pc, vm, 32) DOT16(Pd, vm, 48)
    const int buf = b & 1;
    part_s[buf][hf][g] = (a0 + a1) + (a2 + a3);
    __syncthreads();
    // phase 2 (replicated per wave): update own h = hf*64 + lane
    {
      const float* p0 = part_s[buf][0];
      const float* p1 = part_s[buf][1];
      float gi = p0[h_own] + p1[h_own];
      float gf = p0[h_own + 128] + p1[h_own + 128];
      float gG = p0[h_own + 256] + p1[h_own + 256];
      float go = p0[h_own + 384] + p1[h_own + 384];
      float ii = sigm_fast(gi);
      float ff = sigm_fast(gf);
      float GG = tanh_fast(gG);
      float oo = sigm_fast(go);
      float rst = (memp - thr > 0.f) ? thr : 0.f;  // honest (thr2 runtime)
      syn = ff * syn + ii * GG;
      float mm = oo * tanh_fast(syn) - rst;
      memp = mm;
      accm += mm;
      vm = __float_as_int(mm);
    }
    // no 2nd barrier: next iter writes part_s[buf^1], not the buffer read
  }
  // mean over steps -> FC (8 outputs) -> broadcast to all 512 rows
  if (i < 64) red_s[lane] = accm * (1.f / 256.f);            // wave 0: h=0..63
  if (i >= 512 && i < 576) red_s[64 + lane] = accm * (1.f / 256.f);  // wave 8
  __syncthreads();
  if (i < 8) {
    float s = fc_b[i];
    const float* fw = fc_w + i * H_;
    for (int k = 0; k < H_; ++k) s = fmaf(red_s[k], fw[k], s);
    red_s[H_ + i] = s;
  }
  __syncthreads();
  for (int idx = i; idx < T_ * 8; idx += 1024) out[idx] = red_s[H_ + (idx & 7)];
}

// ---------------- Kernel 6: final mean + FC (fallback only) ----------------
__global__ void k_out(const float* __restrict__ thr1_p,
                      const float* __restrict__ accv,
                      const float* __restrict__ fc_w,
                      const float* __restrict__ fc_b, float* __restrict__ out) {
  if (thr1_p[0] >= 1.0f) return;
  int idx = blockIdx.x * blockDim.x + threadIdx.x;  // t*8+n
  if (idx >= T_ * 8) return;
  int t = idx >> 3, n = idx & 7;
  float s = fc_b[n];
  for (int h = 0; h < H_; ++h)
    s = fmaf(accv[t * H_ + h] * (1.f / 256.f), fc_w[n * H_ + h], s);
  out[idx] = s;
}

extern "C" void kernel_launch(void* const* d_in, const int* in_sizes, int n_in,
                              void* d_out, int out_size, void* d_ws, size_t ws_size,
                              hipStream_t stream) {
  const float* x       = (const float*)d_in[0];
  const float* conv_w  = (const float*)d_in[1];
  const float* conv_b  = (const float*)d_in[2];
  const float* w_ih1   = (const float*)d_in[3];
  const float* w_hh1   = (const float*)d_in[4];
  const float* b_ih1   = (const float*)d_in[5];
  const float* b_hh1   = (const float*)d_in[6];
  const float* thr1    = (const float*)d_in[7];
  const float* w_ih2   = (const float*)d_in[8];
  const float* w_hh2   = (const float*)d_in[9];
  const float* b_ih2   = (const float*)d_in[10];
  const float* b_hh2   = (const float*)d_in[11];
  const float* thr2    = (const float*)d_in[12];
  const float* bn_g    = (const float*)d_in[13];
  const float* bn_b    = (const float*)d_in[14];
  const float* fc_w    = (const float*)d_in[15];
  const float* fc_b    = (const float*)d_in[16];
  float* out = (float*)d_out;

  char* ws = (char*)d_ws;
  unsigned int* cur1       = (unsigned int*)(ws);                    // 512 KB
  unsigned long long* spk  = (unsigned long long*)(ws + (512 << 10));// 2 MB
  unsigned int* count      = (unsigned int*)(ws + (2560 << 10));     // 512 B
  float* a                 = (float*)(ws + (2561 << 10));            // 512 B
  float* c                 = (float*)(ws + (2562 << 10));            // 512 B
  float* cg                = (float*)(ws + (2563 << 10));            // 2 KB
  float* W2p               = (float*)(ws + (2566 << 10));            // 256 KB
  float* accv              = (float*)(ws + (2822 << 10));            // 256 KB

  hipMemsetAsync(count, 0, H_ * sizeof(unsigned int), stream);
  k_conv_spike<<<(B_ * T_ + 255) / 256, 256, 0, stream>>>(thr1, x, conv_w,
                                                          conv_b, cur1);
  k_slstm1<<<T_ / 2, 512, 0, stream>>>(cur1, w_ih1, w_hh1, b_ih1, b_hh1, thr1,
                                       spk, count);
  k_bnprep<<<1, 128, 0, stream>>>(count, bn_g, bn_b, a, c);
  k_fold<<<1, 512, 0, stream>>>(thr1, w_ih2, b_ih2, b_hh2, a, c, W2p, cg);
  k_slstm2<<<T_ / 2, 512, 0, stream>>>(thr1, spk, w_hh2, W2p, cg, thr2, accv);
  k_traj<<<1, 1024, 0, stream>>>(thr1, w_hh2, cg, thr2, fc_w, fc_b, out);
  k_out<<<(T_ * 8 + 255) / 256, 256, 0, stream>>>(thr1, accv, fc_w, fc_b, out);
}

// Round 13
// 323.703 us; speedup vs baseline: 1.0002x; 1.0002x over previous
//
#include <hip/hip_runtime.h>
#include <hip/hip_bf16.h>
#include <stdint.h>

#define B_ 256
#define T_ 512
#define C_ 14
#define CO_ 32
#define H_ 128
#define G_ 512   // 4*H

__device__ __forceinline__ float sigm_fast(float x) {
  float e = __expf(-x);
  return __builtin_amdgcn_rcpf(1.f + e);
}
__device__ __forceinline__ float tanh_fast(float x) {
  float e = __expf(2.f * x);               // inf-safe: x>>0 -> 1, x<<0 -> -1
  return 1.f - 2.f * __builtin_amdgcn_rcpf(1.f + e);
}

// Fast path is provable: mem = o*tanh(syn) - reset*thr < 1 always (o<1,
// |tanh|<1). Spike needs mem - thr1 > 0, impossible when thr1 >= 1, so
// layer-1 spikes are identically zero for ANY x/weights.

// ---------------- Kernel 1: conv over time + Leaky spike (fallback) --------
__global__ __launch_bounds__(256) void k_conv_spike(
    const float* __restrict__ thr1_p, const float* __restrict__ x,
    const float* __restrict__ cw, const float* __restrict__ cb,
    unsigned int* __restrict__ cur1) {
  if (thr1_p[0] >= 1.0f) return;
  __shared__ float w_s[CO_ * C_ * 3];
  __shared__ float b_s[CO_];
  for (int i = threadIdx.x; i < CO_ * C_ * 3; i += blockDim.x) w_s[i] = cw[i];
  if (threadIdx.x < CO_) b_s[threadIdx.x] = cb[threadIdx.x];
  __syncthreads();
  int idx = blockIdx.x * blockDim.x + threadIdx.x;  // b*T + t
  if (idx >= B_ * T_) return;
  int b = idx / T_, t = idx % T_;
  float xin[3][C_];
#pragma unroll
  for (int k = 0; k < 3; ++k) {
    int tt = t + k - 1;
    if (tt < 0 || tt >= T_) {
#pragma unroll
      for (int c = 0; c < C_; ++c) xin[k][c] = 0.f;
    } else {
      const float* p = x + ((size_t)b * T_ + tt) * C_;
#pragma unroll
      for (int c = 0; c < C_; ++c) xin[k][c] = p[c];
    }
  }
  unsigned int bits = 0u;
  for (int oc = 0; oc < CO_; ++oc) {
    float s = b_s[oc];
    const float* wr = &w_s[oc * C_ * 3];
#pragma unroll
    for (int ic = 0; ic < C_; ++ic)
#pragma unroll
      for (int k = 0; k < 3; ++k) s = fmaf(xin[k][ic], wr[ic * 3 + k], s);
    if (s - 1.0f > 0.f) bits |= (1u << oc);
  }
  cur1[idx] = bits;
}

// ---------------- Kernel 2: honest SLSTM layer 1 (fallback only) -----------
__global__ __launch_bounds__(512, 2) void k_slstm1(
    const unsigned int* __restrict__ cur1,
    const float* __restrict__ w_ih, const float* __restrict__ w_hh,
    const float* __restrict__ b_ih, const float* __restrict__ b_hh,
    const float* __restrict__ thr_p, unsigned long long* __restrict__ spk_bits,
    unsigned int* __restrict__ count) {
  if (thr_p[0] >= 1.0f) return;  // spikes provably zero; count stays 0
  const int g = threadIdx.x;
  const int t0 = blockIdx.x * 2;
  const float thr = thr_p[0];
  float wih[32], whh[H_];
#pragma unroll
  for (int k = 0; k < 32; ++k) wih[k] = w_ih[g * 32 + k];
#pragma unroll
  for (int k = 0; k < H_; ++k) whh[k] = w_hh[g * H_ + k];
  const float bias = b_ih[g] + b_hh[g];
  __shared__ float mem_s[2][H_];
  __shared__ float gate_s[2][G_];
  float syn = 0.f;
  int cnt = 0;
  if (g < 256) mem_s[g >> 7][g & 127] = 0.f;
  __syncthreads();
  for (int b = 0; b < B_; ++b) {
    unsigned int bits0 = cur1[b * T_ + t0];
    unsigned int bits1 = cur1[b * T_ + t0 + 1];
    float s0 = bias, s1 = bias;
#pragma unroll
    for (int k = 0; k < 32; ++k) {
      s0 += ((bits0 >> k) & 1u) ? wih[k] : 0.f;
      s1 += ((bits1 >> k) & 1u) ? wih[k] : 0.f;
    }
#pragma unroll
    for (int k = 0; k < H_; ++k) {
      s0 = fmaf(whh[k], mem_s[0][k], s0);
      s1 = fmaf(whh[k], mem_s[1][k], s1);
    }
    gate_s[0][g] = s0;
    gate_s[1][g] = s1;
    __syncthreads();
    if (g < 256) {
      const int r = g >> 7, h = g & 127;
      float gi = gate_s[r][h];
      float gf = gate_s[r][h + 128];
      float gg = gate_s[r][h + 256];
      float go = gate_s[r][h + 384];
      float ii = 1.f / (1.f + expf(-gi));
      float ff = 1.f / (1.f + expf(-gf));
      float gt = tanhf(gg);
      float oo = 1.f / (1.f + expf(-go));
      float memp = mem_s[r][h];
      float rst = (memp - thr > 0.f) ? thr : 0.f;
      syn = ff * syn + ii * gt;
      float mm = oo * tanhf(syn) - rst;
      mem_s[r][h] = mm;
      bool spk = (mm - thr) > 0.f;
      cnt += spk ? 1 : 0;
      unsigned long long m = __ballot(spk);
      if ((g & 63) == 0)
        spk_bits[((size_t)b * T_ + t0 + r) * 2 + ((h >> 6) & 1)] = m;
    }
    __syncthreads();
  }
  if (g < 256) atomicAdd(&count[g & 127], (unsigned int)cnt);
}

// ---------------- Kernel 3: BN params from spike counts (both paths) -------
__global__ void k_bnprep(const unsigned int* __restrict__ count,
                         const float* __restrict__ gamma,
                         const float* __restrict__ beta,
                         float* __restrict__ a, float* __restrict__ c) {
  int h = threadIdx.x;
  if (h >= H_) return;
  const float inv_n = 1.f / (float)(B_ * T_);
  float mu = (float)count[h] * inv_n;
  float var = mu * (1.f - mu);
  float ai = gamma[h] / sqrtf(var + 1e-5f);
  a[h] = ai;
  c[h] = beta[h] - mu * ai;
}

// ---------------- Kernel 4: fold BN into layer-2 weights (cg both paths) ---
__global__ void k_fold(const float* __restrict__ thr1_p,
                       const float* __restrict__ w_ih2,
                       const float* __restrict__ b_ih2,
                       const float* __restrict__ b_hh2,
                       const float* __restrict__ a, const float* __restrict__ c,
                       float* __restrict__ W2p, float* __restrict__ cg) {
  int gi = blockIdx.x * blockDim.x + threadIdx.x;  // 0..511
  if (gi >= G_) return;
  const int fast = thr1_p[0] >= 1.0f;
  float s = b_ih2[gi] + b_hh2[gi];
  for (int h = 0; h < H_; ++h) {
    float w = w_ih2[gi * H_ + h];
    if (!fast) W2p[h * G_ + gi] = w * a[h];  // fallback-only matrix
    s = fmaf(w, c[h], s);
  }
  cg[gi] = s;
}

// ---------------- Kernel 5: honest SLSTM layer 2 (fallback only) -----------
__global__ __launch_bounds__(512, 2) void k_slstm2(
    const float* __restrict__ thr1_p,
    const unsigned long long* __restrict__ spk_bits,
    const float* __restrict__ w_hh, const float* __restrict__ W2p,
    const float* __restrict__ cg, const float* __restrict__ thr_p,
    float* __restrict__ acc_out) {
  if (thr1_p[0] >= 1.0f) return;  // fast path handled by k_traj
  const int g = threadIdx.x;
  const int t0 = blockIdx.x * 2;
  const float thr = thr_p[0];
  float whh[H_];
#pragma unroll
  for (int k = 0; k < H_; ++k) whh[k] = w_hh[g * H_ + k];
  const float bias = cg[g];
  __shared__ float mem_s[2][H_];
  __shared__ float gate_s[2][G_];
  float syn = 0.f, accv = 0.f;
  if (g < 256) mem_s[g >> 7][g & 127] = 0.f;
  __syncthreads();
  for (int b = 0; b < B_; ++b) {
    unsigned long long m00 = spk_bits[((size_t)b * T_ + t0) * 2 + 0];
    unsigned long long m01 = spk_bits[((size_t)b * T_ + t0) * 2 + 1];
    unsigned long long m10 = spk_bits[((size_t)b * T_ + t0 + 1) * 2 + 0];
    unsigned long long m11 = spk_bits[((size_t)b * T_ + t0 + 1) * 2 + 1];
    float s0 = bias, s1 = bias;
    while (m00) { int h = __ffsll(m00) - 1; m00 &= m00 - 1; s0 += W2p[h * G_ + g]; }
    while (m01) { int h = __ffsll(m01) - 1; m01 &= m01 - 1; s0 += W2p[(h + 64) * G_ + g]; }
    while (m10) { int h = __ffsll(m10) - 1; m10 &= m10 - 1; s1 += W2p[h * G_ + g]; }
    while (m11) { int h = __ffsll(m11) - 1; m11 &= m11 - 1; s1 += W2p[(h + 64) * G_ + g]; }
#pragma unroll
    for (int k = 0; k < H_; ++k) {
      s0 = fmaf(whh[k], mem_s[0][k], s0);
      s1 = fmaf(whh[k], mem_s[1][k], s1);
    }
    gate_s[0][g] = s0;
    gate_s[1][g] = s1;
    __syncthreads();
    if (g < 256) {
      const int r = g >> 7, h = g & 127;
      float gi = gate_s[r][h];
      float gf = gate_s[r][h + 128];
      float gg = gate_s[r][h + 256];
      float go = gate_s[r][h + 384];
      float ii = 1.f / (1.f + expf(-gi));
      float ff = 1.f / (1.f + expf(-gf));
      float gt = tanhf(gg);
      float oo = 1.f / (1.f + expf(-go));
      float memp = mem_s[r][h];
      float rst = (memp - thr > 0.f) ? thr : 0.f;
      syn = ff * syn + ii * gt;
      float mm = oo * tanhf(syn) - rst;
      mem_s[r][h] = mm;
      accv += mm;
    }
    __syncthreads();
  }
  if (g < 256) acc_out[(size_t)(t0 + (g >> 7)) * H_ + (g & 127)] = accv;
}

// ---------------- Kernel 5b: FAST layer 2 — single shared trajectory -------
// thr1>=1 -> layer-2 input = beta every row/step -> ONE 256-step trajectory.
// Structure identical to round 12 (1024 thr, half-gate/thread, one-time
// pins, replicated phase-2, 1 barrier/step). ONE change: readlanes are
// BATCHED 8-at-a-time into independent SGPR temps before their FMAs —
// the strict mk=readlane;fma(mk) alternation forced a VALU-writes-SGPR ->
// VALU-reads-SGPR hazard wait state per pair (~64 slots/wave/step, the
// measured +900 cyc/step). Same element->accumulator assignment, so the
// summation tree (and rounding) is unchanged.
#define PIN4(v) asm volatile("" : "+v"(v.x), "+v"(v.y), "+v"(v.z), "+v"(v.w))
#define PIN16(P) PIN4(P##0); PIN4(P##1); PIN4(P##2); PIN4(P##3);

#define LD16(P, p, o)                              \
  float4 P##0 = *(const float4*)((p) + (o));       \
  float4 P##1 = *(const float4*)((p) + (o) + 4);   \
  float4 P##2 = *(const float4*)((p) + (o) + 8);   \
  float4 P##3 = *(const float4*)((p) + (o) + 12);

#define RLF(v, k) __uint_as_float(__builtin_amdgcn_readlane((v), (k)))

// NOTE: (P##0).x — parens required; "P##0.x" lexes "0.x" as one pp-number.
#define DOT16(P, vmx, base) {                                   \
    float m0 = RLF(vmx, (base) + 0), m1 = RLF(vmx, (base) + 1); \
    float m2 = RLF(vmx, (base) + 2), m3 = RLF(vmx, (base) + 3); \
    float m4 = RLF(vmx, (base) + 4), m5 = RLF(vmx, (base) + 5); \
    float m6 = RLF(vmx, (base) + 6), m7 = RLF(vmx, (base) + 7); \
    a0 = fmaf((P##0).x, m0, a0); a1 = fmaf((P##0).y, m1, a1);   \
    a2 = fmaf((P##0).z, m2, a2); a3 = fmaf((P##0).w, m3, a3);   \
    a0 = fmaf((P##1).x, m4, a0); a1 = fmaf((P##1).y, m5, a1);   \
    a2 = fmaf((P##1).z, m6, a2); a3 = fmaf((P##1).w, m7, a3);   \
    m0 = RLF(vmx, (base) + 8);  m1 = RLF(vmx, (base) + 9);      \
    m2 = RLF(vmx, (base) + 10); m3 = RLF(vmx, (base) + 11);     \
    m4 = RLF(vmx, (base) + 12); m5 = RLF(vmx, (base) + 13);     \
    m6 = RLF(vmx, (base) + 14); m7 = RLF(vmx, (base) + 15);     \
    a0 = fmaf((P##2).x, m0, a0); a1 = fmaf((P##2).y, m1, a1);   \
    a2 = fmaf((P##2).z, m2, a2); a3 = fmaf((P##2).w, m3, a3);   \
    a0 = fmaf((P##3).x, m4, a0); a1 = fmaf((P##3).y, m5, a1);   \
    a2 = fmaf((P##3).z, m6, a2); a3 = fmaf((P##3).w, m7, a3);   \
  }

__global__ __launch_bounds__(1024)
__attribute__((amdgpu_waves_per_eu(4, 4))) void k_traj(
    const float* __restrict__ thr1_p, const float* __restrict__ w_hh,
    const float* __restrict__ cg, const float* __restrict__ thr_p,
    const float* __restrict__ fc_w, const float* __restrict__ fc_b,
    float* __restrict__ out) {
  if (thr1_p[0] < 1.0f) return;
  const int i = threadIdx.x;
  const int g = i & 511;     // gate
  const int hf = i >> 9;     // half (wave-uniform: waves 0-7 -> 0, 8-15 -> 1)
  const int lane = i & 63;
  const int h_own = (hf << 6) + lane;   // this thread's hidden index
  const float thr = thr_p[0];

  const float* wr = w_hh + (size_t)g * H_ + (hf << 6);
  LD16(Pa, wr, 0) LD16(Pb, wr, 16) LD16(Pc, wr, 32) LD16(Pd, wr, 48)
  float bias = hf ? 0.f : cg[g];
  // ONE-TIME pins: weights become asm-defined (non-rematerializable),
  // stay register-resident across the loop at zero per-iteration cost.
  PIN16(Pa) PIN16(Pb) PIN16(Pc) PIN16(Pd)
  asm volatile("" : "+v"(bias));

  __shared__ float part_s[2][2][G_];  // [buf][hf][gate] partial preacts
  __shared__ float red_s[H_ + 8];
  float syn = 0.f, memp = 0.f, accm = 0.f;
  int vm = 0;  // bits of mem[hf*64 + lane]; mem_0 = 0

  for (int b = 0; b < B_; ++b) {
    // phase 1: 64-wide half-dot for gate g; operands via batched readlane
    float a0 = bias, a1 = 0.f, a2 = 0.f, a3 = 0.f;
    DOT16(Pa, vm, 0) DOT16(Pb, vm, 16) DOT16(Pc, vm, 32) DOT16(Pd, vm, 48)
    const int buf = b & 1;
    part_s[buf][hf][g] = (a0 + a1) + (a2 + a3);
    __syncthreads();
    // phase 2 (replicated per wave): update own h = hf*64 + lane
    {
      const float* p0 = part_s[buf][0];
      const float* p1 = part_s[buf][1];
      float gi = p0[h_own] + p1[h_own];
      float gf = p0[h_own + 128] + p1[h_own + 128];
      float gG = p0[h_own + 256] + p1[h_own + 256];
      float go = p0[h_own + 384] + p1[h_own + 384];
      float ii = sigm_fast(gi);
      float ff = sigm_fast(gf);
      float GG = tanh_fast(gG);
      float oo = sigm_fast(go);
      float rst = (memp - thr > 0.f) ? thr : 0.f;  // honest (thr2 runtime)
      syn = ff * syn + ii * GG;
      float mm = oo * tanh_fast(syn) - rst;
      memp = mm;
      accm += mm;
      vm = __float_as_int(mm);
    }
    // no 2nd barrier: next iter writes part_s[buf^1], not the buffer read
  }
  // mean over steps -> FC (8 outputs) -> broadcast to all 512 rows
  if (i < 64) red_s[lane] = accm * (1.f / 256.f);            // wave 0: h=0..63
  if (i >= 512 && i < 576) red_s[64 + lane] = accm * (1.f / 256.f);  // wave 8
  __syncthreads();
  if (i < 8) {
    float s = fc_b[i];
    const float* fw = fc_w + i * H_;
    for (int k = 0; k < H_; ++k) s = fmaf(red_s[k], fw[k], s);
    red_s[H_ + i] = s;
  }
  __syncthreads();
  for (int idx = i; idx < T_ * 8; idx += 1024) out[idx] = red_s[H_ + (idx & 7)];
}

// ---------------- Kernel 6: final mean + FC (fallback only) ----------------
__global__ void k_out(const float* __restrict__ thr1_p,
                      const float* __restrict__ accv,
                      const float* __restrict__ fc_w,
                      const float* __restrict__ fc_b, float* __restrict__ out) {
  if (thr1_p[0] >= 1.0f) return;
  int idx = blockIdx.x * blockDim.x + threadIdx.x;  // t*8+n
  if (idx >= T_ * 8) return;
  int t = idx >> 3, n = idx & 7;
  float s = fc_b[n];
  for (int h = 0; h < H_; ++h)
    s = fmaf(accv[t * H_ + h] * (1.f / 256.f), fc_w[n * H_ + h], s);
  out[idx] = s;
}

extern "C" void kernel_launch(void* const* d_in, const int* in_sizes, int n_in,
                              void* d_out, int out_size, void* d_ws, size_t ws_size,
                              hipStream_t stream) {
  const float* x       = (const float*)d_in[0];
  const float* conv_w  = (const float*)d_in[1];
  const float* conv_b  = (const float*)d_in[2];
  const float* w_ih1   = (const float*)d_in[3];
  const float* w_hh1   = (const float*)d_in[4];
  const float* b_ih1   = (const float*)d_in[5];
  const float* b_hh1   = (const float*)d_in[6];
  const float* thr1    = (const float*)d_in[7];
  const float* w_ih2   = (const float*)d_in[8];
  const float* w_hh2   = (const float*)d_in[9];
  const float* b_ih2   = (const float*)d_in[10];
  const float* b_hh2   = (const float*)d_in[11];
  const float* thr2    = (const float*)d_in[12];
  const float* bn_g    = (const float*)d_in[13];
  const float* bn_b    = (const float*)d_in[14];
  const float* fc_w    = (const float*)d_in[15];
  const float* fc_b    = (const float*)d_in[16];
  float* out = (float*)d_out;

  char* ws = (char*)d_ws;
  unsigned int* cur1       = (unsigned int*)(ws);                    // 512 KB
  unsigned long long* spk  = (unsigned long long*)(ws + (512 << 10));// 2 MB
  unsigned int* count      = (unsigned int*)(ws + (2560 << 10));     // 512 B
  float* a                 = (float*)(ws + (2561 << 10));            // 512 B
  float* c                 = (float*)(ws + (2562 << 10));            // 512 B
  float* cg                = (float*)(ws + (2563 << 10));            // 2 KB
  float* W2p               = (float*)(ws + (2566 << 10));            // 256 KB
  float* accv              = (float*)(ws + (2822 << 10));            // 256 KB

  hipMemsetAsync(count, 0, H_ * sizeof(unsigned int), stream);
  k_conv_spike<<<(B_ * T_ + 255) / 256, 256, 0, stream>>>(thr1, x, conv_w,
                                                          conv_b, cur1);
  k_slstm1<<<T_ / 2, 512, 0, stream>>>(cur1, w_ih1, w_hh1, b_ih1, b_hh1, thr1,
                                       spk, count);
  k_bnprep<<<1, 128, 0, stream>>>(count, bn_g, bn_b, a, c);
  k_fold<<<1, 512, 0, stream>>>(thr1, w_ih2, b_ih2, b_hh2, a, c, W2p, cg);
  k_slstm2<<<T_ / 2, 512, 0, stream>>>(thr1, spk, w_hh2, W2p, cg, thr2, accv);
  k_traj<<<1, 1024, 0, stream>>>(thr1, w_hh2, cg, thr2, fc_w, fc_b, out);
  k_out<<<(T_ * 8 + 255) / 256, 256, 0, stream>>>(thr1, accv, fc_w, fc_b, out);
}

// Round 15
// 287.162 us; speedup vs baseline: 1.1275x; 1.1272x over previous
//
#include <hip/hip_runtime.h>
#include <hip/hip_bf16.h>
#include <stdint.h>

#define B_ 256
#define T_ 512
#define C_ 14
#define CO_ 32
#define H_ 128
#define G_ 512   // 4*H

__device__ __forceinline__ float sigm_fast(float x) {
  float e = __expf(-x);
  return __builtin_amdgcn_rcpf(1.f + e);
}
__device__ __forceinline__ float tanh_fast(float x) {
  float e = __expf(2.f * x);               // inf-safe: x>>0 -> 1, x<<0 -> -1
  return 1.f - 2.f * __builtin_amdgcn_rcpf(1.f + e);
}

// Fast path is provable: mem = o*tanh(syn) - reset*thr < 1 always (o<1,
// |tanh|<1). Spike needs mem - thr1 > 0, impossible when thr1 >= 1, so
// layer-1 spikes are identically zero for ANY x/weights.

// ---------------- Kernel 1: conv over time + Leaky spike (fallback) --------
__global__ __launch_bounds__(256) void k_conv_spike(
    const float* __restrict__ thr1_p, const float* __restrict__ x,
    const float* __restrict__ cw, const float* __restrict__ cb,
    unsigned int* __restrict__ cur1) {
  if (thr1_p[0] >= 1.0f) return;
  __shared__ float w_s[CO_ * C_ * 3];
  __shared__ float b_s[CO_];
  for (int i = threadIdx.x; i < CO_ * C_ * 3; i += blockDim.x) w_s[i] = cw[i];
  if (threadIdx.x < CO_) b_s[threadIdx.x] = cb[threadIdx.x];
  __syncthreads();
  int idx = blockIdx.x * blockDim.x + threadIdx.x;  // b*T + t
  if (idx >= B_ * T_) return;
  int b = idx / T_, t = idx % T_;
  float xin[3][C_];
#pragma unroll
  for (int k = 0; k < 3; ++k) {
    int tt = t + k - 1;
    if (tt < 0 || tt >= T_) {
#pragma unroll
      for (int c = 0; c < C_; ++c) xin[k][c] = 0.f;
    } else {
      const float* p = x + ((size_t)b * T_ + tt) * C_;
#pragma unroll
      for (int c = 0; c < C_; ++c) xin[k][c] = p[c];
    }
  }
  unsigned int bits = 0u;
  for (int oc = 0; oc < CO_; ++oc) {
    float s = b_s[oc];
    const float* wr = &w_s[oc * C_ * 3];
#pragma unroll
    for (int ic = 0; ic < C_; ++ic)
#pragma unroll
      for (int k = 0; k < 3; ++k) s = fmaf(xin[k][ic], wr[ic * 3 + k], s);
    if (s - 1.0f > 0.f) bits |= (1u << oc);
  }
  cur1[idx] = bits;
}

// ---------------- Kernel 2: honest SLSTM layer 1 (fallback only) -----------
__global__ __launch_bounds__(512, 2) void k_slstm1(
    const unsigned int* __restrict__ cur1,
    const float* __restrict__ w_ih, const float* __restrict__ w_hh,
    const float* __restrict__ b_ih, const float* __restrict__ b_hh,
    const float* __restrict__ thr_p, unsigned long long* __restrict__ spk_bits,
    unsigned int* __restrict__ count) {
  if (thr_p[0] >= 1.0f) return;  // spikes provably zero; count stays 0
  const int g = threadIdx.x;
  const int t0 = blockIdx.x * 2;
  const float thr = thr_p[0];
  float wih[32], whh[H_];
#pragma unroll
  for (int k = 0; k < 32; ++k) wih[k] = w_ih[g * 32 + k];
#pragma unroll
  for (int k = 0; k < H_; ++k) whh[k] = w_hh[g * H_ + k];
  const float bias = b_ih[g] + b_hh[g];
  __shared__ float mem_s[2][H_];
  __shared__ float gate_s[2][G_];
  float syn = 0.f;
  int cnt = 0;
  if (g < 256) mem_s[g >> 7][g & 127] = 0.f;
  __syncthreads();
  for (int b = 0; b < B_; ++b) {
    unsigned int bits0 = cur1[b * T_ + t0];
    unsigned int bits1 = cur1[b * T_ + t0 + 1];
    float s0 = bias, s1 = bias;
#pragma unroll
    for (int k = 0; k < 32; ++k) {
      s0 += ((bits0 >> k) & 1u) ? wih[k] : 0.f;
      s1 += ((bits1 >> k) & 1u) ? wih[k] : 0.f;
    }
#pragma unroll
    for (int k = 0; k < H_; ++k) {
      s0 = fmaf(whh[k], mem_s[0][k], s0);
      s1 = fmaf(whh[k], mem_s[1][k], s1);
    }
    gate_s[0][g] = s0;
    gate_s[1][g] = s1;
    __syncthreads();
    if (g < 256) {
      const int r = g >> 7, h = g & 127;
      float gi = gate_s[r][h];
      float gf = gate_s[r][h + 128];
      float gg = gate_s[r][h + 256];
      float go = gate_s[r][h + 384];
      float ii = 1.f / (1.f + expf(-gi));
      float ff = 1.f / (1.f + expf(-gf));
      float gt = tanhf(gg);
      float oo = 1.f / (1.f + expf(-go));
      float memp = mem_s[r][h];
      float rst = (memp - thr > 0.f) ? thr : 0.f;
      syn = ff * syn + ii * gt;
      float mm = oo * tanhf(syn) - rst;
      mem_s[r][h] = mm;
      bool spk = (mm - thr) > 0.f;
      cnt += spk ? 1 : 0;
      unsigned long long m = __ballot(spk);
      if ((g & 63) == 0)
        spk_bits[((size_t)b * T_ + t0 + r) * 2 + ((h >> 6) & 1)] = m;
    }
    __syncthreads();
  }
  if (g < 256) atomicAdd(&count[g & 127], (unsigned int)cnt);
}

// ---------------- Kernel 3: BN params from spike counts (both paths) -------
__global__ void k_bnprep(const unsigned int* __restrict__ count,
                         const float* __restrict__ gamma,
                         const float* __restrict__ beta,
                         float* __restrict__ a, float* __restrict__ c) {
  int h = threadIdx.x;
  if (h >= H_) return;
  const float inv_n = 1.f / (float)(B_ * T_);
  float mu = (float)count[h] * inv_n;
  float var = mu * (1.f - mu);
  float ai = gamma[h] / sqrtf(var + 1e-5f);
  a[h] = ai;
  c[h] = beta[h] - mu * ai;
}

// ---------------- Kernel 4: fold BN into layer-2 weights (cg both paths) ---
__global__ void k_fold(const float* __restrict__ thr1_p,
                       const float* __restrict__ w_ih2,
                       const float* __restrict__ b_ih2,
                       const float* __restrict__ b_hh2,
                       const float* __restrict__ a, const float* __restrict__ c,
                       float* __restrict__ W2p, float* __restrict__ cg) {
  int gi = blockIdx.x * blockDim.x + threadIdx.x;  // 0..511
  if (gi >= G_) return;
  const int fast = thr1_p[0] >= 1.0f;
  float s = b_ih2[gi] + b_hh2[gi];
  for (int h = 0; h < H_; ++h) {
    float w = w_ih2[gi * H_ + h];
    if (!fast) W2p[h * G_ + gi] = w * a[h];  // fallback-only matrix
    s = fmaf(w, c[h], s);
  }
  cg[gi] = s;
}

// ---------------- Kernel 5: honest SLSTM layer 2 (fallback only) -----------
__global__ __launch_bounds__(512, 2) void k_slstm2(
    const float* __restrict__ thr1_p,
    const unsigned long long* __restrict__ spk_bits,
    const float* __restrict__ w_hh, const float* __restrict__ W2p,
    const float* __restrict__ cg, const float* __restrict__ thr_p,
    float* __restrict__ acc_out) {
  if (thr1_p[0] >= 1.0f) return;  // fast path handled by k_traj
  const int g = threadIdx.x;
  const int t0 = blockIdx.x * 2;
  const float thr = thr_p[0];
  float whh[H_];
#pragma unroll
  for (int k = 0; k < H_; ++k) whh[k] = w_hh[g * H_ + k];
  const float bias = cg[g];
  __shared__ float mem_s[2][H_];
  __shared__ float gate_s[2][G_];
  float syn = 0.f, accv = 0.f;
  if (g < 256) mem_s[g >> 7][g & 127] = 0.f;
  __syncthreads();
  for (int b = 0; b < B_; ++b) {
    unsigned long long m00 = spk_bits[((size_t)b * T_ + t0) * 2 + 0];
    unsigned long long m01 = spk_bits[((size_t)b * T_ + t0) * 2 + 1];
    unsigned long long m10 = spk_bits[((size_t)b * T_ + t0 + 1) * 2 + 0];
    unsigned long long m11 = spk_bits[((size_t)b * T_ + t0 + 1) * 2 + 1];
    float s0 = bias, s1 = bias;
    while (m00) { int h = __ffsll(m00) - 1; m00 &= m00 - 1; s0 += W2p[h * G_ + g]; }
    while (m01) { int h = __ffsll(m01) - 1; m01 &= m01 - 1; s0 += W2p[(h + 64) * G_ + g]; }
    while (m10) { int h = __ffsll(m10) - 1; m10 &= m10 - 1; s1 += W2p[h * G_ + g]; }
    while (m11) { int h = __ffsll(m11) - 1; m11 &= m11 - 1; s1 += W2p[(h + 64) * G_ + g]; }
#pragma unroll
    for (int k = 0; k < H_; ++k) {
      s0 = fmaf(whh[k], mem_s[0][k], s0);
      s1 = fmaf(whh[k], mem_s[1][k], s1);
    }
    gate_s[0][g] = s0;
    gate_s[1][g] = s1;
    __syncthreads();
    if (g < 256) {
      const int r = g >> 7, h = g & 127;
      float gi = gate_s[r][h];
      float gf = gate_s[r][h + 128];
      float gg = gate_s[r][h + 256];
      float go = gate_s[r][h + 384];
      float ii = 1.f / (1.f + expf(-gi));
      float ff = 1.f / (1.f + expf(-gf));
      float gt = tanhf(gg);
      float oo = 1.f / (1.f + expf(-go));
      float memp = mem_s[r][h];
      float rst = (memp - thr > 0.f) ? thr : 0.f;
      syn = ff * syn + ii * gt;
      float mm = oo * tanhf(syn) - rst;
      mem_s[r][h] = mm;
      accv += mm;
    }
    __syncthreads();
  }
  if (g < 256) acc_out[(size_t)(t0 + (g >> 7)) * H_ + (g & 127)] = accv;
}

// ---------------- Kernel 5b: FAST layer 2 — single shared trajectory -------
// thr1>=1 -> layer-2 input = beta every row/step -> ONE 256-step trajectory.
// Round-13 finding: v_readlane issues at ~4cyc -> 64 RL/wave/step (~1000
// cyc/step across 4 waves/SIMD) was the bottleneck. Fix: mem is WAVE-
// UNIFORM state -> load it through the SCALAR pipe (s_load_dwordx16 x2,
// ~free VALU-wise); FMAs take mem as their one SGPR operand.
// Coherence without K$ games: phase 2 stores each step's mem to a FRESH
// 512B slice of a global ring (mem_hist[257][128]) -> every K$ line is
// cold at read time, so s_load is served from L2; the vmcnt(0) inside
// __syncthreads guarantees L2 is up to date; K$ is invalidated at kernel
// dispatch, so graph replays are safe.
// Round-14 compile fix: LLVM does NOT auto-readfirstlane an "s"-constrained
// input it can't prove uniform (emitted v[76:77] into s_load). Force the
// address uniform with __builtin_amdgcn_readfirstlane on both halves
// (semantically a no-op: qt is wave-uniform, b is loop-uniform).
#define PIN4(v) asm volatile("" : "+v"(v.x), "+v"(v.y), "+v"(v.z), "+v"(v.w))
#define PIN16(P) PIN4(P##0); PIN4(P##1); PIN4(P##2); PIN4(P##3);

#define LD16(P, p, o)                              \
  float4 P##0 = *(const float4*)((p) + (o));       \
  float4 P##1 = *(const float4*)((p) + (o) + 4);   \
  float4 P##2 = *(const float4*)((p) + (o) + 8);   \
  float4 P##3 = *(const float4*)((p) + (o) + 12);

typedef int v16i __attribute__((ext_vector_type(16)));

// P4/Q4: float4 weight regs (gate A / gate B); V: v16i of mem bits;
// j0: element offset. fmaf(v, s, v): one SGPR operand — legal VOP3.
#define FQ(P4, Q4, V, j0) {                                       \
    float m0 = __int_as_float((V)[(j0) + 0]);                     \
    float m1 = __int_as_float((V)[(j0) + 1]);                     \
    float m2 = __int_as_float((V)[(j0) + 2]);                     \
    float m3 = __int_as_float((V)[(j0) + 3]);                     \
    a0 = fmaf((P4).x, m0, a0); b0 = fmaf((Q4).x, m0, b0);         \
    a1 = fmaf((P4).y, m1, a1); b1 = fmaf((Q4).y, m1, b1);         \
    a2 = fmaf((P4).z, m2, a2); b2 = fmaf((Q4).z, m2, b2);         \
    a3 = fmaf((P4).w, m3, a3); b3 = fmaf((Q4).w, m3, b3);         \
  }

__global__ __launch_bounds__(1024)
__attribute__((amdgpu_waves_per_eu(4, 4))) void k_traj(
    const float* __restrict__ thr1_p, const float* __restrict__ w_hh,
    const float* __restrict__ cg, const float* __restrict__ thr_p,
    const float* __restrict__ fc_w, const float* __restrict__ fc_b,
    float* __restrict__ mem_hist, float* __restrict__ out) {
  if (thr1_p[0] < 1.0f) return;
  const int i = threadIdx.x;
  const int g0 = i & 255;          // this thread's low gate; also g0+256
  const int qt = (i >> 8) & 3;     // k-quarter, wave-uniform
  const float thr = thr_p[0];

  const float* wA = w_hh + (size_t)g0 * H_ + qt * 32;
  const float* wB = w_hh + (size_t)(g0 + 256) * H_ + qt * 32;
  LD16(Pa, wA, 0) LD16(Pb, wA, 16)   // gate A: k-rel 0..15, 16..31
  LD16(Qa, wB, 0) LD16(Qb, wB, 16)   // gate B
  float biasA = (qt == 0) ? cg[g0] : 0.f;
  float biasB = (qt == 0) ? cg[g0 + 256] : 0.f;
  // one-time pins: non-rematerializable, register-resident, no loop cost
  PIN16(Pa) PIN16(Pb) PIN16(Qa) PIN16(Qb)
  asm volatile("" : "+v"(biasA), "+v"(biasB));

  __shared__ float part_s[4][G_];    // [quarter][gate]
  __shared__ float red_s[H_ + 8];
  float syn = 0.f, memp = 0.f, accm = 0.f;   // live in owners (i<128)

  for (int b = 0; b < B_; ++b) {
    // phase 1: scalar-pipe broadcast of mem (uniform) into 32 SGPRs
    const unsigned long long a64 =
        (unsigned long long)(size_t)(mem_hist + (size_t)b * H_ + qt * 32);
    const unsigned int alo = __builtin_amdgcn_readfirstlane((unsigned int)a64);
    const unsigned int ahi =
        __builtin_amdgcn_readfirstlane((unsigned int)(a64 >> 32));
    const unsigned long long sa64 = (((unsigned long long)ahi) << 32) | alo;
    v16i sa, sb;
    asm volatile(
        "s_load_dwordx16 %0, %2, 0\n\t"
        "s_load_dwordx16 %1, %2, 64\n\t"
        "s_waitcnt lgkmcnt(0)"
        : "=s"(sa), "=s"(sb)
        : "s"(sa64)
        : "memory");
    float a0 = biasA, a1 = 0.f, a2 = 0.f, a3 = 0.f;
    float b0 = biasB, b1 = 0.f, b2 = 0.f, b3 = 0.f;
    FQ(Pa0, Qa0, sa, 0) FQ(Pa1, Qa1, sa, 4)
    FQ(Pa2, Qa2, sa, 8) FQ(Pa3, Qa3, sa, 12)
    FQ(Pb0, Qb0, sb, 0) FQ(Pb1, Qb1, sb, 4)
    FQ(Pb2, Qb2, sb, 8) FQ(Pb3, Qb3, sb, 12)
    part_s[qt][g0] = (a0 + a1) + (a2 + a3);
    part_s[qt][g0 + 256] = (b0 + b1) + (b2 + b3);
    __syncthreads();
    // phase 2: owners (threads 0..127) finish their h = i
    if (i < H_) {
      float gi = (part_s[0][i] + part_s[1][i]) + (part_s[2][i] + part_s[3][i]);
      float gf = (part_s[0][i + 128] + part_s[1][i + 128]) +
                 (part_s[2][i + 128] + part_s[3][i + 128]);
      float gG = (part_s[0][i + 256] + part_s[1][i + 256]) +
                 (part_s[2][i + 256] + part_s[3][i + 256]);
      float go = (part_s[0][i + 384] + part_s[1][i + 384]) +
                 (part_s[2][i + 384] + part_s[3][i + 384]);
      float ii = sigm_fast(gi);
      float ff = sigm_fast(gf);
      float GG = tanh_fast(gG);
      float oo = sigm_fast(go);
      float rst = (memp - thr > 0.f) ? thr : 0.f;  // honest (thr2 runtime)
      syn = ff * syn + ii * GG;
      float mm = oo * tanh_fast(syn) - rst;
      memp = mm;
      accm += mm;
      mem_hist[(size_t)(b + 1) * H_ + i] = mm;   // fresh slice every step
    }
    __syncthreads();  // vmcnt(0) inside guarantees L2 visibility for s_load
  }
  // mean over steps -> FC (8 outputs) -> broadcast to all 512 rows
  if (i < H_) red_s[i] = accm * (1.f / 256.f);
  __syncthreads();
  if (i < 8) {
    float s = fc_b[i];
    const float* fw = fc_w + i * H_;
    for (int k = 0; k < H_; ++k) s = fmaf(red_s[k], fw[k], s);
    red_s[H_ + i] = s;
  }
  __syncthreads();
  for (int idx = i; idx < T_ * 8; idx += 1024) out[idx] = red_s[H_ + (idx & 7)];
}

// ---------------- Kernel 6: final mean + FC (fallback only) ----------------
__global__ void k_out(const float* __restrict__ thr1_p,
                      const float* __restrict__ accv,
                      const float* __restrict__ fc_w,
                      const float* __restrict__ fc_b, float* __restrict__ out) {
  if (thr1_p[0] >= 1.0f) return;
  int idx = blockIdx.x * blockDim.x + threadIdx.x;  // t*8+n
  if (idx >= T_ * 8) return;
  int t = idx >> 3, n = idx & 7;
  float s = fc_b[n];
  for (int h = 0; h < H_; ++h)
    s = fmaf(accv[t * H_ + h] * (1.f / 256.f), fc_w[n * H_ + h], s);
  out[idx] = s;
}

extern "C" void kernel_launch(void* const* d_in, const int* in_sizes, int n_in,
                              void* d_out, int out_size, void* d_ws, size_t ws_size,
                              hipStream_t stream) {
  const float* x       = (const float*)d_in[0];
  const float* conv_w  = (const float*)d_in[1];
  const float* conv_b  = (const float*)d_in[2];
  const float* w_ih1   = (const float*)d_in[3];
  const float* w_hh1   = (const float*)d_in[4];
  const float* b_ih1   = (const float*)d_in[5];
  const float* b_hh1   = (const float*)d_in[6];
  const float* thr1    = (const float*)d_in[7];
  const float* w_ih2   = (const float*)d_in[8];
  const float* w_hh2   = (const float*)d_in[9];
  const float* b_ih2   = (const float*)d_in[10];
  const float* b_hh2   = (const float*)d_in[11];
  const float* thr2    = (const float*)d_in[12];
  const float* bn_g    = (const float*)d_in[13];
  const float* bn_b    = (const float*)d_in[14];
  const float* fc_w    = (const float*)d_in[15];
  const float* fc_b    = (const float*)d_in[16];
  float* out = (float*)d_out;

  char* ws = (char*)d_ws;
  // mem_hist (fast-path only, 257*128*4 = 129KB) ALIASES the cur1 region
  // (fallback-only): in fallback, k_traj exits before touching it and the
  // 512B memset below happens before k_conv_spike writes cur1.
  float* mem_hist          = (float*)(ws);
  unsigned int* cur1       = (unsigned int*)(ws);                    // 512 KB
  unsigned long long* spk  = (unsigned long long*)(ws + (512 << 10));// 2 MB
  unsigned int* count      = (unsigned int*)(ws + (2560 << 10));     // 512 B
  float* a                 = (float*)(ws + (2561 << 10));            // 512 B
  float* c                 = (float*)(ws + (2562 << 10));            // 512 B
  float* cg                = (float*)(ws + (2563 << 10));            // 2 KB
  float* W2p               = (float*)(ws + (2566 << 10));            // 256 KB
  float* accv              = (float*)(ws + (2822 << 10));            // 256 KB

  (void)hipMemsetAsync(count, 0, H_ * sizeof(unsigned int), stream);
  (void)hipMemsetAsync(mem_hist, 0, H_ * sizeof(float), stream);  // mem step 0
  k_conv_spike<<<(B_ * T_ + 255) / 256, 256, 0, stream>>>(thr1, x, conv_w,
                                                          conv_b, cur1);
  k_slstm1<<<T_ / 2, 512, 0, stream>>>(cur1, w_ih1, w_hh1, b_ih1, b_hh1, thr1,
                                       spk, count);
  k_bnprep<<<1, 128, 0, stream>>>(count, bn_g, bn_b, a, c);
  k_fold<<<1, 512, 0, stream>>>(thr1, w_ih2, b_ih2, b_hh2, a, c, W2p, cg);
  k_slstm2<<<T_ / 2, 512, 0, stream>>>(thr1, spk, w_hh2, W2p, cg, thr2, accv);
  k_traj<<<1, 1024, 0, stream>>>(thr1, w_hh2, cg, thr2, fc_w, fc_b, mem_hist,
                                 out);
  k_out<<<(T_ * 8 + 255) / 256, 256, 0, stream>>>(thr1, accv, fc_w, fc_b, out);
}